// Round 9
// baseline (2047.974 us; speedup 1.0000x reference)
//
#include <hip/hip_runtime.h>
#include <stdint.h>

#define T_SEQ 128
#define B_SZ  32
#define H_DIM 1024
#define E_DIM 512
#define V_DIM 32000
#define SOS_TOK 1
#define NCONS 480        // consumer blocks (32-col panels, 2 blocks/CU)
#define NPAN  1000       // 32000 / 32 panels

typedef float v4f __attribute__((ext_vector_type(4)));
typedef short short8 __attribute__((ext_vector_type(8)));

// RNE float->bf16
__device__ inline uint16_t f2bf(float x) {
    uint32_t u = __float_as_uint(x);
    uint32_t r = (u + 0x7fffu + ((u >> 16) & 1u)) >> 16;
    return (uint16_t)r;
}
__device__ inline uint32_t pack2(float a, float b) {
    return (uint32_t)f2bf(a) | ((uint32_t)f2bf(b) << 16);
}

// async global->LDS, 16B per lane. lds base must be wave-uniform.
__device__ inline void gload16(const void* g, void* l) {
    __builtin_amdgcn_global_load_lds(
        (const __attribute__((address_space(1))) uint32_t*)g,
        (__attribute__((address_space(3))) uint32_t*)l, 16, 0, 0);
}

// ---------------------------------------------------------------------------
// kconv: fp32 -> bf16, 2048 elements per block
// ---------------------------------------------------------------------------
__global__ __launch_bounds__(256) void kconv(const float* __restrict__ W,
                                             uint16_t* __restrict__ Wb) {
    size_t i = ((size_t)blockIdx.x * 256 + threadIdx.x) * 8;
    float4 a = *(const float4*)&W[i];
    float4 c = *(const float4*)&W[i + 4];
    uint4 p;
    p.x = pack2(a.x, a.y); p.y = pack2(a.z, a.w);
    p.z = pack2(c.x, c.y); p.w = pack2(c.z, c.w);
    *(uint4*)&Wb[i] = p;
}

// ---------------------------------------------------------------------------
// kxwm: xW[t*B+b][n] = emb[tok(b,t)] . Wih[n] + bih[n] + bhh[n]   (bf16 MFMA)
// ---------------------------------------------------------------------------
__global__ __launch_bounds__(256) void kxwm(const int* __restrict__ target,
                                            const float* __restrict__ emb,
                                            const float* __restrict__ Wih,
                                            const float* __restrict__ bih,
                                            const float* __restrict__ bhh,
                                            float* __restrict__ xW) {
    __shared__ __align__(16) uint16_t As[128 * 32];
    __shared__ __align__(16) uint16_t Bs[128 * 32];
    __shared__ int toks[128];
    int m0 = blockIdx.x * 128, n0 = blockIdx.y * 128;
    int tid = threadIdx.x;
    if (tid < 128) {
        int row = m0 + tid;
        int t = row & (T_SEQ - 1);
        toks[tid] = (t == 0) ? SOS_TOK : target[row];
    }
    __syncthreads();

    v4f acc[4][4] = {};
    int lane = tid & 63, wv = tid >> 6, wm = wv >> 1, wn = wv & 1;
    int ar = lane & 15, ko = (lane >> 4) * 8;

    for (int k0 = 0; k0 < E_DIM; k0 += 32) {
#pragma unroll
        for (int l = 0; l < 2; ++l) {
            int c = tid + l * 256;
            int r = c >> 2, ko8 = (c & 3) * 8;
            const float* asrc = &emb[(size_t)toks[r] * E_DIM + k0 + ko8];
            float4 x = *(const float4*)asrc;
            float4 y = *(const float4*)(asrc + 4);
            uint4 p;
            p.x = pack2(x.x, x.y); p.y = pack2(x.z, x.w);
            p.z = pack2(y.x, y.y); p.w = pack2(y.z, y.w);
            *(uint4*)&As[r * 32 + ko8] = p;
            const float* bsrc = &Wih[(size_t)(n0 + r) * E_DIM + k0 + ko8];
            float4 u = *(const float4*)bsrc;
            float4 v = *(const float4*)(bsrc + 4);
            uint4 q;
            q.x = pack2(u.x, u.y); q.y = pack2(u.z, u.w);
            q.z = pack2(v.x, v.y); q.w = pack2(v.z, v.w);
            *(uint4*)&Bs[r * 32 + ko8] = q;
        }
        __syncthreads();

        short8 a[4], bfr[4];
#pragma unroll
        for (int i = 0; i < 4; ++i)
            a[i] = *(const short8*)&As[(wm * 64 + i * 16 + ar) * 32 + ko];
#pragma unroll
        for (int jj = 0; jj < 4; ++jj)
            bfr[jj] = *(const short8*)&Bs[(wn * 64 + jj * 16 + ar) * 32 + ko];
#pragma unroll
        for (int i = 0; i < 4; ++i)
#pragma unroll
            for (int jj = 0; jj < 4; ++jj)
                acc[i][jj] = __builtin_amdgcn_mfma_f32_16x16x32_bf16(
                    a[i], bfr[jj], acc[i][jj], 0, 0, 0);
        __syncthreads();
    }

    int fr = lane & 15, fq = lane >> 4;
#pragma unroll
    for (int jj = 0; jj < 4; ++jj) {
        int col = n0 + wn * 64 + jj * 16 + fr;
        float bias = bih[col] + bhh[col];
#pragma unroll
        for (int i = 0; i < 4; ++i) {
            int row = m0 + wm * 64 + i * 16 + fq * 4;
#pragma unroll
            for (int q = 0; q < 4; ++q) {
                int m = row + q;                 // = b*T + t
                int b = m >> 7, t = m & (T_SEQ - 1);
                xW[((size_t)t * B_SZ + b) * H_DIM + col] = acc[i][jj][q] + bias;
            }
        }
    }
}

// ---------------------------------------------------------------------------
// kfused: 512 blocks x 256 thr (fully resident: 72KB LDS -> 2 blocks/CU).
//  blocks 0..31   : recurrence producers — EXACT R6/R8-proven body (tanhf,
//                   setprio(1), per-step distributed-flag barrier, 8-copy
//                   epoch publication by ngg==0 blocks, final epoch=128).
//  blocks 32..511 : decode consumers, PANEL-RESIDENT: consumer c owns W_out
//                   panels {c, c+480, (c<40) c+960} of 32 cols. Per panel:
//                   stage panel ONCE into LDS (fp32->bf16, XOR-swizzled
//                   ((col&7)<<4) on the byte offset), then loop ALL 32 mtp
//                   tiles against it. A = Hb 128x32 K-slab per step via
//                   source-swizzled global_load_lds (R7-proven, 0 conflicts).
//                   W_out is read from HBM exactly once chip-wide (131 MB).
//                   Gates: 2-lane epoch poll, monotone need=4*mtp+4.
// ---------------------------------------------------------------------------
__global__ __launch_bounds__(256) void kfused(const uint16_t* __restrict__ hbInit,
                                              const uint16_t* __restrict__ WbHH,
                                              const float* __restrict__ xW,
                                              uint16_t* __restrict__ Hb,
                                              uint32_t* __restrict__ flags,
                                              uint32_t* __restrict__ epochs,
                                              const float* __restrict__ Wout,
                                              const float* __restrict__ bout,
                                              float* __restrict__ out) {
    __shared__ __align__(16) uint16_t Bp[32 * 1024];   // 64 KB B panel
    __shared__ __align__(16) uint16_t As[128 * 32];    //  8 KB A slab
    int tid = threadIdx.x;
    int lane = tid & 63;

    if (blockIdx.x < 32) {
        // ---------------- producer: recurrence (R6 body) ----------------
        __builtin_amdgcn_s_setprio(1);
        int blk = blockIdx.x;
        int bg = blk & 1, ngg = blk >> 1;
        int w = tid >> 6;
        int ncol0 = ngg * 64 + w * 16;
        int lr = lane & 15, lk = (lane >> 4) * 8;

        short8 wf[32];
        const uint16_t* wrow = WbHH + (size_t)(ncol0 + lr) * H_DIM + lk;
#pragma unroll
        for (int kt = 0; kt < 32; ++kt)
            wf[kt] = *(const short8*)(wrow + (size_t)kt * 32);

        int brow = bg * 16 + lr;
        int eb = bg * 16 + (lane >> 4) * 4;
        int en = ncol0 + lr;
        uint32_t* Hb32 = (uint32_t*)Hb;
        uint32_t* myflag = flags + (size_t)(bg * 16 + ngg) * 32;
        const uint32_t* grpflags = flags + (size_t)(bg * 16) * 32;

        for (int t = 0; t < T_SEQ; ++t) {
            const uint16_t* arow =
                ((t == 0) ? hbInit : Hb + (size_t)(t - 1) * B_SZ * H_DIM)
                + (size_t)brow * H_DIM + lk;

            float xv[4];
#pragma unroll
            for (int q = 0; q < 4; ++q)
                xv[q] = xW[((size_t)t * B_SZ + eb + q) * H_DIM + en];

            v4f ac0 = {0.f,0.f,0.f,0.f}, ac1 = {0.f,0.f,0.f,0.f};
            v4f ac2 = {0.f,0.f,0.f,0.f}, ac3 = {0.f,0.f,0.f,0.f};
            short8 af[16];
#pragma unroll
            for (int kt = 0; kt < 16; ++kt)
                af[kt] = *(const short8*)(arow + (size_t)kt * 32);
#pragma unroll
            for (int kt = 0; kt < 16; ++kt) {
                v4f* a = (kt & 3) == 0 ? &ac0 : (kt & 3) == 1 ? &ac1
                        : (kt & 3) == 2 ? &ac2 : &ac3;
                *a = __builtin_amdgcn_mfma_f32_16x16x32_bf16(af[kt], wf[kt], *a, 0, 0, 0);
            }
#pragma unroll
            for (int kt = 0; kt < 16; ++kt)
                af[kt] = *(const short8*)(arow + 512 + (size_t)kt * 32);
#pragma unroll
            for (int kt = 0; kt < 16; ++kt) {
                v4f* a = (kt & 3) == 0 ? &ac0 : (kt & 3) == 1 ? &ac1
                        : (kt & 3) == 2 ? &ac2 : &ac3;
                *a = __builtin_amdgcn_mfma_f32_16x16x32_bf16(af[kt], wf[16 + kt], *a, 0, 0, 0);
            }
            v4f acc = (ac0 + ac1) + (ac2 + ac3);

            float hv[4];
#pragma unroll
            for (int q = 0; q < 4; ++q)
                hv[q] = tanhf(acc[q] + xv[q]);

            // publish write-through: pair lanes -> 4B words, 2 stores/lane
#pragma unroll
            for (int q = 0; q < 4; ++q) {
                float pv = __shfl_xor(hv[q], 1);
                bool mine = ((lane & 1) == 0) ? (q < 2) : (q >= 2);
                if (mine) {
                    uint32_t word = (lane & 1) ? pack2(pv, hv[q]) : pack2(hv[q], pv);
                    size_t i32 = (((size_t)t * B_SZ + eb + q) * H_DIM
                                  + (size_t)(en & ~1)) >> 1;
                    __hip_atomic_store(&Hb32[i32], word, __ATOMIC_RELAXED,
                                       __HIP_MEMORY_SCOPE_AGENT);
                }
            }

            __syncthreads();   // drain all waves' stores before arrival
            if (tid == 0)
                __hip_atomic_store(myflag, (uint32_t)(t + 1), __ATOMIC_RELEASE,
                                   __HIP_MEMORY_SCOPE_AGENT);
            if (t < T_SEQ - 1) {
                if (tid < 16) {
                    const uint32_t* f = grpflags + (size_t)tid * 32;
                    while (__hip_atomic_load(f, __ATOMIC_RELAXED,
                                             __HIP_MEMORY_SCOPE_AGENT) <= (uint32_t)t)
                        __builtin_amdgcn_s_sleep(2);
                }
                if (tid == 0)
                    (void)__hip_atomic_load(myflag, __ATOMIC_ACQUIRE,
                                            __HIP_MEMORY_SCOPE_AGENT);
                __syncthreads();
                // epoch publication: group flags all >= t+1 observed
                if (ngg == 0 && tid < 8) {
                    __builtin_amdgcn_fence(__ATOMIC_ACQUIRE, "agent");
                    __hip_atomic_store(epochs + (size_t)(bg * 8 + tid) * 32,
                                       (uint32_t)(t + 1), __ATOMIC_RELEASE,
                                       __HIP_MEMORY_SCOPE_AGENT);
                }
            }
        }
        // final epoch = T_SEQ
        if (ngg == 0) {
            if (tid < 16) {
                const uint32_t* f = grpflags + (size_t)tid * 32;
                while (__hip_atomic_load(f, __ATOMIC_RELAXED,
                                         __HIP_MEMORY_SCOPE_AGENT) < (uint32_t)T_SEQ)
                    __builtin_amdgcn_s_sleep(2);
            }
            __syncthreads();
            if (tid < 8) {
                __builtin_amdgcn_fence(__ATOMIC_ACQUIRE, "agent");
                __hip_atomic_store(epochs + (size_t)(bg * 8 + tid) * 32,
                                   (uint32_t)T_SEQ, __ATOMIC_RELEASE,
                                   __HIP_MEMORY_SCOPE_AGENT);
            }
        }
    } else {
        // ---------------- consumer: panel-resident decode GEMM -----------
        int c = blockIdx.x - 32;
        int wv = tid >> 6, wm = wv >> 1, wn = wv & 1;   // 2M x 2N wave grid
        int ar = lane & 15;
        int ko = (lane >> 4) * 8;                 // A k-granule (elements)
        int sx = ((ar >> 1) & 3) << 3;            // A frag-read swizzle (elems)
        int fq = lane >> 4;
        int cp = blockIdx.x & 7;                  // epoch copy
        const uint32_t* ep0 = epochs + (size_t)cp * 32;
        const uint32_t* ep1 = epochs + (size_t)(8 + cp) * 32;
        int gate_seen = 0;

        int bcol = wn * 16 + ar;                  // this lane's panel column
        int bswz = (bcol & 7) << 4;               // B byte-offset XOR

        for (int pp = c; pp < NPAN; pp += NCONS) {
            int n0 = pp * 32;
            // ---- stage B panel once: Wout fp32 -> bf16, swizzled ----
#pragma unroll 4
            for (int j = 0; j < 16; ++j) {
                int g = tid + 256 * j;            // 0..4095 granules of 8
                int col = g >> 7;                 // 0..31
                int kk = (g & 127) * 8;           // 0..1016
                const float* src = &Wout[(size_t)(n0 + col) * H_DIM + kk];
                float4 x = *(const float4*)src;
                float4 y = *(const float4*)(src + 4);
                uint4 p;
                p.x = pack2(x.x, x.y); p.y = pack2(x.z, x.w);
                p.z = pack2(y.x, y.y); p.w = pack2(y.z, y.w);
                int off = (col << 11) + ((kk * 2) ^ ((col & 7) << 4));
                *(uint4*)((char*)Bp + off) = p;
            }
            float bo = bout[n0 + bcol];
            __syncthreads();                      // panel visible to all waves

            for (int mtp = 0; mtp < 32; ++mtp) {
                int need = 4 * mtp + 4;
                if (need > gate_seen) {
                    if (tid == 0) {
                        while (__hip_atomic_load(ep0, __ATOMIC_RELAXED,
                                                 __HIP_MEMORY_SCOPE_AGENT) < (uint32_t)need)
                            __builtin_amdgcn_s_sleep(15);
                    } else if (tid == 1) {
                        while (__hip_atomic_load(ep1, __ATOMIC_RELAXED,
                                                 __HIP_MEMORY_SCOPE_AGENT) < (uint32_t)need)
                            __builtin_amdgcn_s_sleep(15);
                    }
                    __syncthreads();
                    __builtin_amdgcn_fence(__ATOMIC_ACQUIRE, "agent");
                    gate_seen = need;
                }

                int m0 = mtp * 128;
                v4f acc[4] = {};

                for (int k0 = 0; k0 < H_DIM; k0 += 32) {
                    int wb = tid & ~63;
#pragma unroll
                    for (int l = 0; l < 2; ++l) {
                        int cc = tid + l * 256;
                        int r = cc >> 2;
                        int gsw = ((cc & 3) ^ ((cc >> 3) & 3)) * 8;
                        gload16(&Hb[(size_t)(m0 + r) * H_DIM + k0 + gsw],
                                (char*)As + (size_t)(wb + l * 256) * 16);
                    }
                    __syncthreads();

                    short8 b = *(const short8*)((const char*)Bp + (bcol << 11)
                                 + ((((k0 >> 3) + (lane >> 4)) << 4) ^ bswz));
                    short8 a[4];
#pragma unroll
                    for (int i = 0; i < 4; ++i)
                        a[i] = *(const short8*)&As[(wm * 64 + i * 16 + ar) * 32 + (ko ^ sx)];
#pragma unroll
                    for (int i = 0; i < 4; ++i)
                        acc[i] = __builtin_amdgcn_mfma_f32_16x16x32_bf16(
                            a[i], b, acc[i], 0, 0, 0);
                    __syncthreads();
                }

                // epilogue: lane owns col n0+bcol, 16 rows
#pragma unroll
                for (int i = 0; i < 4; ++i) {
#pragma unroll
                    for (int q = 0; q < 4; ++q) {
                        int mp = m0 + wm * 64 + i * 16 + fq * 4 + q;  // t*B+b
                        int tt = mp >> 5, bb = mp & 31;
                        out[((size_t)bb * T_SEQ + tt) * V_DIM + n0 + bcol] =
                            acc[i][q] + bo;
                    }
                }
            }
        }
    }
}

// ---------------------------------------------------------------------------
extern "C" void kernel_launch(void* const* d_in, const int* in_sizes, int n_in,
                              void* d_out, int out_size, void* d_ws, size_t ws_size,
                              hipStream_t stream) {
    const int*   target = (const int*)d_in[0];
    const float* h0     = (const float*)d_in[1];
    const float* emb    = (const float*)d_in[2];
    const float* Wih    = (const float*)d_in[3];
    const float* bih    = (const float*)d_in[4];
    const float* Whh    = (const float*)d_in[5];
    const float* bhh    = (const float*)d_in[6];
    const float* Wout   = (const float*)d_in[7];
    const float* bout   = (const float*)d_in[8];
    float* out = (float*)d_out;

    char* ws = (char*)d_ws;
    // ws layout (bytes) — total 27,334,656:
    float*    xW     = (float*)(ws);                    // 16,777,216
    uint16_t* WbHH   = (uint16_t*)(ws + 16777216);      //  2,097,152
    uint16_t* hbInit = (uint16_t*)(ws + 18874368);      //     65,536
    uint32_t* flags  = (uint32_t*)(ws + 18939904);      //      4,096
    uint32_t* epochs = (uint32_t*)(ws + 18944000);      //      2,048
    uint16_t* Hb     = (uint16_t*)(ws + 18946048);      //  8,388,608

    kconv<<<512, 256, 0, stream>>>(Whh, WbHH);       // 1,048,576 elts
    kconv<<<16, 256, 0, stream>>>(h0, hbInit);       //    32,768 elts
    kxwm<<<dim3(32, 8), 256, 0, stream>>>(target, emb, Wih, bih, bhh, xW);
    hipMemsetAsync(flags, 0, 6144, stream);
    kfused<<<32 + NCONS, 256, 0, stream>>>(hbInit, WbHH, xW, Hb, flags, epochs,
                                           Wout, bout, out);
}

// Round 10
// 1661.135 us; speedup vs baseline: 1.2329x; 1.2329x over previous
//
#include <hip/hip_runtime.h>
#include <stdint.h>

#define T_SEQ 128
#define B_SZ  32
#define H_DIM 1024
#define E_DIM 512
#define V_DIM 32000
#define SOS_TOK 1
#define NCONS 480        // consumer blocks; 32-col panels
#define NPAN  1000       // 32000 / 32

typedef float v4f __attribute__((ext_vector_type(4)));
typedef short short8 __attribute__((ext_vector_type(8)));

// RNE float->bf16
__device__ inline uint16_t f2bf(float x) {
    uint32_t u = __float_as_uint(x);
    uint32_t r = (u + 0x7fffu + ((u >> 16) & 1u)) >> 16;
    return (uint16_t)r;
}
__device__ inline uint32_t pack2(float a, float b) {
    return (uint32_t)f2bf(a) | ((uint32_t)f2bf(b) << 16);
}

// ---------------------------------------------------------------------------
// kconv: fp32 -> bf16, 2048 elements per block
// ---------------------------------------------------------------------------
__global__ __launch_bounds__(256) void kconv(const float* __restrict__ W,
                                             uint16_t* __restrict__ Wb) {
    size_t i = ((size_t)blockIdx.x * 256 + threadIdx.x) * 8;
    float4 a = *(const float4*)&W[i];
    float4 c = *(const float4*)&W[i + 4];
    uint4 p;
    p.x = pack2(a.x, a.y); p.y = pack2(a.z, a.w);
    p.z = pack2(c.x, c.y); p.w = pack2(c.z, c.w);
    *(uint4*)&Wb[i] = p;
}

// ---------------------------------------------------------------------------
// kxwm: xW[t*B+b][n] = emb[tok(b,t)] . Wih[n] + bih[n] + bhh[n]   (bf16 MFMA)
// ---------------------------------------------------------------------------
__global__ __launch_bounds__(256) void kxwm(const int* __restrict__ target,
                                            const float* __restrict__ emb,
                                            const float* __restrict__ Wih,
                                            const float* __restrict__ bih,
                                            const float* __restrict__ bhh,
                                            float* __restrict__ xW) {
    __shared__ __align__(16) uint16_t As[128 * 32];
    __shared__ __align__(16) uint16_t Bs[128 * 32];
    __shared__ int toks[128];
    int m0 = blockIdx.x * 128, n0 = blockIdx.y * 128;
    int tid = threadIdx.x;
    if (tid < 128) {
        int row = m0 + tid;
        int t = row & (T_SEQ - 1);
        toks[tid] = (t == 0) ? SOS_TOK : target[row];
    }
    __syncthreads();

    v4f acc[4][4] = {};
    int lane = tid & 63, wv = tid >> 6, wm = wv >> 1, wn = wv & 1;
    int ar = lane & 15, ko = (lane >> 4) * 8;

    for (int k0 = 0; k0 < E_DIM; k0 += 32) {
#pragma unroll
        for (int l = 0; l < 2; ++l) {
            int c = tid + l * 256;
            int r = c >> 2, ko8 = (c & 3) * 8;
            const float* asrc = &emb[(size_t)toks[r] * E_DIM + k0 + ko8];
            float4 x = *(const float4*)asrc;
            float4 y = *(const float4*)(asrc + 4);
            uint4 p;
            p.x = pack2(x.x, x.y); p.y = pack2(x.z, x.w);
            p.z = pack2(y.x, y.y); p.w = pack2(y.z, y.w);
            *(uint4*)&As[r * 32 + ko8] = p;
            const float* bsrc = &Wih[(size_t)(n0 + r) * E_DIM + k0 + ko8];
            float4 u = *(const float4*)bsrc;
            float4 v = *(const float4*)(bsrc + 4);
            uint4 q;
            q.x = pack2(u.x, u.y); q.y = pack2(u.z, u.w);
            q.z = pack2(v.x, v.y); q.w = pack2(v.z, v.w);
            *(uint4*)&Bs[r * 32 + ko8] = q;
        }
        __syncthreads();

        short8 a[4], bfr[4];
#pragma unroll
        for (int i = 0; i < 4; ++i)
            a[i] = *(const short8*)&As[(wm * 64 + i * 16 + ar) * 32 + ko];
#pragma unroll
        for (int jj = 0; jj < 4; ++jj)
            bfr[jj] = *(const short8*)&Bs[(wn * 64 + jj * 16 + ar) * 32 + ko];
#pragma unroll
        for (int i = 0; i < 4; ++i)
#pragma unroll
            for (int jj = 0; jj < 4; ++jj)
                acc[i][jj] = __builtin_amdgcn_mfma_f32_16x16x32_bf16(
                    a[i], bfr[jj], acc[i][jj], 0, 0, 0);
        __syncthreads();
    }

    int fr = lane & 15, fq = lane >> 4;
#pragma unroll
    for (int jj = 0; jj < 4; ++jj) {
        int col = n0 + wn * 64 + jj * 16 + fr;
        float bias = bih[col] + bhh[col];
#pragma unroll
        for (int i = 0; i < 4; ++i) {
            int row = m0 + wm * 64 + i * 16 + fq * 4;
#pragma unroll
            for (int q = 0; q < 4; ++q) {
                int m = row + q;                 // = b*T + t
                int b = m >> 7, t = m & (T_SEQ - 1);
                xW[((size_t)t * B_SZ + b) * H_DIM + col] = acc[i][jj][q] + bias;
            }
        }
    }
}

// ---------------------------------------------------------------------------
// kfused: 512 blocks x 256 thr (64KB LDS -> 2 blocks/CU, fully resident).
//  blocks 0..31   : recurrence producers — EXACT R9 body (proven): tanhf,
//                   setprio(1), per-step distributed-flag barrier, 8-copy
//                   epoch publication by ngg==0 blocks, final epoch=128.
//  blocks 32..511 : decode consumers. B panel (32 cols x 1024 K, bf16,
//                   XOR-swizzled) LDS-resident; A-frags read DIRECTLY from
//                   global Hb (no A-LDS, no per-K-step barriers). Wave w owns
//                   whole 128x32 tiles mtp = lo+w, lo+w+4, ... ; per-wave
//                   epoch gating (broadcast poll + wave acquire fence).
//                   Panels banded across the producer timeline:
//                     2 panels: (p1 0..23)(p2 0..31)(p1 24..31)
//                     3 panels: (p1 0..15)(p2 0..23)(p3 0..31)
//                               (p1 16..31)(p2 24..31)
//                   so the post-producer tail is ~1-2 tiles/wave.
// ---------------------------------------------------------------------------
__global__ __launch_bounds__(256) void kfused(const uint16_t* __restrict__ hbInit,
                                              const uint16_t* __restrict__ WbHH,
                                              const float* __restrict__ xW,
                                              uint16_t* __restrict__ Hb,
                                              uint32_t* __restrict__ flags,
                                              uint32_t* __restrict__ epochs,
                                              const float* __restrict__ Wout,
                                              const float* __restrict__ bout,
                                              float* __restrict__ out) {
    __shared__ __align__(16) uint16_t Bp[32 * 1024];   // 64 KB B panel
    int tid = threadIdx.x;
    int lane = tid & 63;

    if (blockIdx.x < 32) {
        // ---------------- producer: recurrence (R9 body, verbatim) --------
        __builtin_amdgcn_s_setprio(1);
        int blk = blockIdx.x;
        int bg = blk & 1, ngg = blk >> 1;
        int w = tid >> 6;
        int ncol0 = ngg * 64 + w * 16;
        int lr = lane & 15, lk = (lane >> 4) * 8;

        short8 wf[32];
        const uint16_t* wrow = WbHH + (size_t)(ncol0 + lr) * H_DIM + lk;
#pragma unroll
        for (int kt = 0; kt < 32; ++kt)
            wf[kt] = *(const short8*)(wrow + (size_t)kt * 32);

        int brow = bg * 16 + lr;
        int eb = bg * 16 + (lane >> 4) * 4;
        int en = ncol0 + lr;
        uint32_t* Hb32 = (uint32_t*)Hb;
        uint32_t* myflag = flags + (size_t)(bg * 16 + ngg) * 32;
        const uint32_t* grpflags = flags + (size_t)(bg * 16) * 32;

        for (int t = 0; t < T_SEQ; ++t) {
            const uint16_t* arow =
                ((t == 0) ? hbInit : Hb + (size_t)(t - 1) * B_SZ * H_DIM)
                + (size_t)brow * H_DIM + lk;

            float xv[4];
#pragma unroll
            for (int q = 0; q < 4; ++q)
                xv[q] = xW[((size_t)t * B_SZ + eb + q) * H_DIM + en];

            v4f ac0 = {0.f,0.f,0.f,0.f}, ac1 = {0.f,0.f,0.f,0.f};
            v4f ac2 = {0.f,0.f,0.f,0.f}, ac3 = {0.f,0.f,0.f,0.f};
            short8 af[16];
#pragma unroll
            for (int kt = 0; kt < 16; ++kt)
                af[kt] = *(const short8*)(arow + (size_t)kt * 32);
#pragma unroll
            for (int kt = 0; kt < 16; ++kt) {
                v4f* a = (kt & 3) == 0 ? &ac0 : (kt & 3) == 1 ? &ac1
                        : (kt & 3) == 2 ? &ac2 : &ac3;
                *a = __builtin_amdgcn_mfma_f32_16x16x32_bf16(af[kt], wf[kt], *a, 0, 0, 0);
            }
#pragma unroll
            for (int kt = 0; kt < 16; ++kt)
                af[kt] = *(const short8*)(arow + 512 + (size_t)kt * 32);
#pragma unroll
            for (int kt = 0; kt < 16; ++kt) {
                v4f* a = (kt & 3) == 0 ? &ac0 : (kt & 3) == 1 ? &ac1
                        : (kt & 3) == 2 ? &ac2 : &ac3;
                *a = __builtin_amdgcn_mfma_f32_16x16x32_bf16(af[kt], wf[16 + kt], *a, 0, 0, 0);
            }
            v4f acc = (ac0 + ac1) + (ac2 + ac3);

            float hv[4];
#pragma unroll
            for (int q = 0; q < 4; ++q)
                hv[q] = tanhf(acc[q] + xv[q]);

#pragma unroll
            for (int q = 0; q < 4; ++q) {
                float pv = __shfl_xor(hv[q], 1);
                bool mine = ((lane & 1) == 0) ? (q < 2) : (q >= 2);
                if (mine) {
                    uint32_t word = (lane & 1) ? pack2(pv, hv[q]) : pack2(hv[q], pv);
                    size_t i32 = (((size_t)t * B_SZ + eb + q) * H_DIM
                                  + (size_t)(en & ~1)) >> 1;
                    __hip_atomic_store(&Hb32[i32], word, __ATOMIC_RELAXED,
                                       __HIP_MEMORY_SCOPE_AGENT);
                }
            }

            __syncthreads();   // drain all waves' stores before arrival
            if (tid == 0)
                __hip_atomic_store(myflag, (uint32_t)(t + 1), __ATOMIC_RELEASE,
                                   __HIP_MEMORY_SCOPE_AGENT);
            if (t < T_SEQ - 1) {
                if (tid < 16) {
                    const uint32_t* f = grpflags + (size_t)tid * 32;
                    while (__hip_atomic_load(f, __ATOMIC_RELAXED,
                                             __HIP_MEMORY_SCOPE_AGENT) <= (uint32_t)t)
                        __builtin_amdgcn_s_sleep(2);
                }
                if (tid == 0)
                    (void)__hip_atomic_load(myflag, __ATOMIC_ACQUIRE,
                                            __HIP_MEMORY_SCOPE_AGENT);
                __syncthreads();
                if (ngg == 0 && tid < 8) {
                    __builtin_amdgcn_fence(__ATOMIC_ACQUIRE, "agent");
                    __hip_atomic_store(epochs + (size_t)(bg * 8 + tid) * 32,
                                       (uint32_t)(t + 1), __ATOMIC_RELEASE,
                                       __HIP_MEMORY_SCOPE_AGENT);
                }
            }
        }
        if (ngg == 0) {
            if (tid < 16) {
                const uint32_t* f = grpflags + (size_t)tid * 32;
                while (__hip_atomic_load(f, __ATOMIC_RELAXED,
                                         __HIP_MEMORY_SCOPE_AGENT) < (uint32_t)T_SEQ)
                    __builtin_amdgcn_s_sleep(2);
            }
            __syncthreads();
            if (tid < 8) {
                __builtin_amdgcn_fence(__ATOMIC_ACQUIRE, "agent");
                __hip_atomic_store(epochs + (size_t)(bg * 8 + tid) * 32,
                                   (uint32_t)T_SEQ, __ATOMIC_RELEASE,
                                   __HIP_MEMORY_SCOPE_AGENT);
            }
        }
    } else {
        // ---------------- consumer: barrier-free panel decode -------------
        int c = blockIdx.x - 32;
        int w = tid >> 6;
        int ar = lane & 15, kg = lane >> 4;
        int fq = kg, fr = ar;
        int cp = (blockIdx.x + w) & 7;
        const uint32_t* ep0 = epochs + (size_t)cp * 32;
        const uint32_t* ep1 = epochs + (size_t)(8 + cp) * 32;
        uint32_t gate_seen = 0;

        int bbase0 = (ar << 11);             // col ar
        int bbase1 = ((16 + ar) << 11);      // col 16+ar
        int bxor = (ar & 7) << 4;            // same for both cols

        // stage panel pp into Bp (fp32 -> bf16, XOR-swizzled granules)
        auto stage = [&](int pp) {
            int n0 = pp * 32;
            __syncthreads();                 // prior readers done
#pragma unroll 4
            for (int j = 0; j < 16; ++j) {
                int g = tid + 256 * j;       // 0..4095 granules of 8 elems
                int col = g >> 7;
                int kk = (g & 127) * 8;
                const float* src = &Wout[(size_t)(n0 + col) * H_DIM + kk];
                float4 x = *(const float4*)src;
                float4 y = *(const float4*)(src + 4);
                uint4 p;
                p.x = pack2(x.x, x.y); p.y = pack2(x.z, x.w);
                p.z = pack2(y.x, y.y); p.w = pack2(y.z, y.w);
                int off = (col << 11) + ((kk * 2) ^ ((col & 7) << 4));
                *(uint4*)((char*)Bp + off) = p;
            }
            __syncthreads();
        };

        // process tiles mtp = mlo+w, +4 ... <= mhi against staged panel pp
        auto do_pass = [&](int pp, int mlo, int mhi) {
            int n0 = pp * 32;
            float bo0 = bout[n0 + fr];
            float bo1 = bout[n0 + 16 + fr];
            for (int mtp = mlo + w; mtp <= mhi; mtp += 4) {
                uint32_t need = (uint32_t)(4 * mtp + 4);
                if (need > gate_seen) {
                    for (;;) {
                        uint32_t a = __hip_atomic_load(ep0, __ATOMIC_RELAXED,
                                                       __HIP_MEMORY_SCOPE_AGENT);
                        uint32_t b = __hip_atomic_load(ep1, __ATOMIC_RELAXED,
                                                       __HIP_MEMORY_SCOPE_AGENT);
                        if (a >= need && b >= need) break;
                        __builtin_amdgcn_s_sleep(15);
                    }
                    __builtin_amdgcn_fence(__ATOMIC_ACQUIRE, "agent");
                    gate_seen = need;
                }

                int m0 = mtp * 128;
                const uint16_t* abase = Hb + (size_t)(m0 + ar) * H_DIM + kg * 8;
                v4f acc[8][2] = {};
#pragma unroll 4
                for (int k0 = 0; k0 < H_DIM; k0 += 32) {
                    int bko = (((k0 >> 3) + kg) << 4) ^ bxor;
                    short8 b0 = *(const short8*)((const char*)Bp + bbase0 + bko);
                    short8 b1 = *(const short8*)((const char*)Bp + bbase1 + bko);
                    short8 a[8];
#pragma unroll
                    for (int i = 0; i < 8; ++i)
                        a[i] = *(const short8*)(abase + (size_t)i * 16 * H_DIM + k0);
#pragma unroll
                    for (int i = 0; i < 8; ++i) {
                        acc[i][0] = __builtin_amdgcn_mfma_f32_16x16x32_bf16(
                            a[i], b0, acc[i][0], 0, 0, 0);
                        acc[i][1] = __builtin_amdgcn_mfma_f32_16x16x32_bf16(
                            a[i], b1, acc[i][1], 0, 0, 0);
                    }
                }
#pragma unroll
                for (int i = 0; i < 8; ++i) {
                    int rbase = m0 + i * 16 + fq * 4;
#pragma unroll
                    for (int q = 0; q < 4; ++q) {
                        int mp = rbase + q;               // row in [t][b] space
                        int tt = mp >> 5, bb = mp & 31;
                        size_t orow = ((size_t)bb * T_SEQ + tt) * V_DIM + n0;
                        out[orow + fr]      = acc[i][0][q] + bo0;
                        out[orow + 16 + fr] = acc[i][1][q] + bo1;
                    }
                }
            }
        };

        int p1 = c, p2 = c + NCONS, p3 = c + 2 * NCONS;
        if (p3 < NPAN) {
            stage(p1); do_pass(p1, 0, 15);
            stage(p2); do_pass(p2, 0, 23);
            stage(p3); do_pass(p3, 0, 31);
            stage(p1); do_pass(p1, 16, 31);
            stage(p2); do_pass(p2, 24, 31);
        } else {
            stage(p1); do_pass(p1, 0, 23);
            stage(p2); do_pass(p2, 0, 31);
            stage(p1); do_pass(p1, 24, 31);
        }
    }
}

// ---------------------------------------------------------------------------
extern "C" void kernel_launch(void* const* d_in, const int* in_sizes, int n_in,
                              void* d_out, int out_size, void* d_ws, size_t ws_size,
                              hipStream_t stream) {
    const int*   target = (const int*)d_in[0];
    const float* h0     = (const float*)d_in[1];
    const float* emb    = (const float*)d_in[2];
    const float* Wih    = (const float*)d_in[3];
    const float* bih    = (const float*)d_in[4];
    const float* Whh    = (const float*)d_in[5];
    const float* bhh    = (const float*)d_in[6];
    const float* Wout   = (const float*)d_in[7];
    const float* bout   = (const float*)d_in[8];
    float* out = (float*)d_out;

    char* ws = (char*)d_ws;
    // ws layout (bytes) — total 27,334,656:
    float*    xW     = (float*)(ws);                    // 16,777,216
    uint16_t* WbHH   = (uint16_t*)(ws + 16777216);      //  2,097,152
    uint16_t* hbInit = (uint16_t*)(ws + 18874368);      //     65,536
    uint32_t* flags  = (uint32_t*)(ws + 18939904);      //      4,096
    uint32_t* epochs = (uint32_t*)(ws + 18944000);      //      2,048
    uint16_t* Hb     = (uint16_t*)(ws + 18946048);      //  8,388,608

    kconv<<<512, 256, 0, stream>>>(Whh, WbHH);       // 1,048,576 elts
    kconv<<<16, 256, 0, stream>>>(h0, hbInit);       //    32,768 elts
    kxwm<<<dim3(32, 8), 256, 0, stream>>>(target, emb, Wih, bih, bhh, xW);
    hipMemsetAsync(flags, 0, 6144, stream);
    kfused<<<32 + NCONS, 256, 0, stream>>>(hbInit, WbHH, xW, Hb, flags, epochs,
                                           Wout, bout, out);
}